// Round 17
// baseline (2414.332 us; speedup 1.0000x reference)
//
#include <hip/hip_runtime.h>

// ---------------------------------------------------------------------------
// MoleRec pipeline on gfx950.
// R16: nodes counting-sorted by degree within each graph region (we own the
//      internal node numbering). Phase A's serial edge loop runs to the MAX
//      degree among a wave's 8 nodes (exec mask); Poisson(2.33) degrees make
//      E[max of 8] ~ 2x the mean. Sorted tiles are degree-uniform -> waves
//      run at ~mean depth. perm/iperm built by histogram + wave scan +
//      assign; scatter/embed/npool updated; GIN kernel itself unchanged.
// ---------------------------------------------------------------------------

typedef short short8 __attribute__((ext_vector_type(8)));
typedef unsigned short us8 __attribute__((ext_vector_type(8)));
typedef float f32x4 __attribute__((ext_vector_type(4)));
typedef unsigned short us4 __attribute__((ext_vector_type(4)));
typedef unsigned int u32;

#define BN_RSQ 0.9999950000374997f   // 1/sqrt(1+1e-5)  (BatchNorm eval, var=1)
#define LN_EPS 1e-5f
#define NEGBIG -4294967296.0f        // -(1<<32), matches reference mask fill

__device__ __forceinline__ unsigned short f2bf(float x) {
  union { float f; unsigned int u; } v; v.f = x;
  unsigned int r = v.u + 0x7fffu + ((v.u >> 16) & 1u);   // RNE
  return (unsigned short)(r >> 16);
}
__device__ __forceinline__ float bf2f(unsigned short x) {
  union { unsigned int u; float f; } v; v.u = ((unsigned int)x) << 16;
  return v.f;
}

// ---------------- fused prep: weights + bond tables + mask detect -----------
__global__ __launch_bounds__(256) void prep_all(
    const float* __restrict__ w1, const float* __restrict__ w2,
    unsigned short* __restrict__ w1t, unsigned short* __restrict__ w2t,
    const float* __restrict__ bond, unsigned short* __restrict__ bt16, int bonde,
    const unsigned char* __restrict__ m, int* __restrict__ flags, int maskn) {
  __shared__ int lf[2];
  int b = blockIdx.x;
  if (b < 1024) {
    int i = b * 256 + threadIdx.x;
    int gl = i >> 15;
    int k1 = (i >> 8) & 127, c1 = i & 255;
    w1t[(gl << 15) + c1 * 128 + k1] = f2bf(w1[i]);
    int k2 = (i >> 7) & 255, c2 = i & 127;
    w2t[(gl << 15) + c2 * 256 + k2] = f2bf(w2[i]);
    return;
  }
  if (b < 1792) {
    int i = (b - 1024) * 256 + threadIdx.x;
    if (i < bonde) bt16[i] = f2bf(bond[i]);
    return;
  }
  if (threadIdx.x == 0) { lf[0] = 0; lf[1] = 0; }
  __syncthreads();
  int f0 = 0, f1 = 0;
  for (int i = (b - 1792) * 256 + threadIdx.x; i < maskn; i += 64 * 256) {
    if (m[i]) { if ((i & 3) == 0) f0 = 1; else f1 = 1; }
  }
  if (f0) atomicOr(&lf[0], 1);
  if (f1) atomicOr(&lf[1], 1);
  __syncthreads();
  if (threadIdx.x == 0) {
    if (lf[0]) atomicOr(flags, 1);
    if (lf[1]) atomicOr(flags + 1, 1);
  }
}

// ---------------- degree count over compact old ids + batch counts ----------
__global__ void build_count_old(const int* __restrict__ ei_m, int Em,
                                const int* __restrict__ ei_s, int Es,
                                const int* __restrict__ bm, int Nm,
                                const int* __restrict__ bs, int Ns,
                                int* __restrict__ deg_old, int* __restrict__ deg_n, int M) {
  int i = blockIdx.x * 256 + threadIdx.x;
  if (i < Em) { atomicAdd(&deg_old[ei_m[i]], 1); return; }
  i -= Em;
  if (i < Es) { atomicAdd(&deg_old[Nm + ei_s[i]], 1); return; }
  i -= Es;
  if (i < Nm) { atomicAdd(&deg_n[bm[i]], 1); return; }
  i -= Nm;
  if (i < Ns) { atomicAdd(&deg_n[M + bs[i]], 1); }
}

// ---------------- degree histogram (2 regions x 64 bins) --------------------
__global__ void deg_hist(const int* __restrict__ deg_old, int Nm, int Ntot,
                         int* __restrict__ hist) {
  int i = blockIdx.x * 256 + threadIdx.x;
  if (i >= Ntot) return;
  int d = deg_old[i]; if (d > 63) d = 63;
  int r = (i < Nm) ? 0 : 1;
  atomicAdd(&hist[r * 64 + d], 1);
}

// ---------------- per-region exclusive scan of 64 bins ----------------------
__global__ __launch_bounds__(128) void hist_scan(const int* __restrict__ hist,
                                                 int* __restrict__ binbase) {
  int t = threadIdx.x;                // 0..127, wave per region
  int lane = t & 63;
  int v = hist[t];
  int x = v;
#pragma unroll
  for (int off = 1; off < 64; off <<= 1) {
    int y = __shfl_up(x, off, 64);
    if (lane >= off) x += y;
  }
  binbase[t] = x - v;
}

// ---------------- assign perm/iperm + permuted degrees ----------------------
__global__ void perm_assign(const int* __restrict__ deg_old, int Nm, int Ntot, int NmR,
                            const int* __restrict__ binbase, int* __restrict__ bincur,
                            int* __restrict__ perm, int* __restrict__ iperm,
                            int* __restrict__ deg_new) {
  int i = blockIdx.x * 256 + threadIdx.x;
  if (i >= Ntot) return;
  int dg = deg_old[i];
  int d = (dg > 63) ? 63 : dg;
  int r = (i < Nm) ? 0 : 1;
  int slot = binbase[r * 64 + d] + atomicAdd(&bincur[r * 64 + d], 1);
  int nid = (r ? NmR : 0) + slot;
  perm[i] = nid;
  iperm[nid] = i;
  deg_new[nid] = dg;
}

// ---------------- fused block scans (edges then nodes) ----------------------
__global__ __launch_bounds__(256) void scan_block2(
    const int* __restrict__ cntE, int nE, int* __restrict__ exclE, int* __restrict__ bsumE, int nbE,
    const int* __restrict__ cntN, int nN, int* __restrict__ exclN, int* __restrict__ bsumN) {
  const int* cnt; int n; int* excl; int* bsum; int blk;
  if (blockIdx.x < (unsigned)nbE) { cnt = cntE; n = nE; excl = exclE; bsum = bsumE; blk = blockIdx.x; }
  else { cnt = cntN; n = nN; excl = exclN; bsum = bsumN; blk = blockIdx.x - nbE; }
  int gid = blk * 256 + threadIdx.x;
  int lane = threadIdx.x & 63, w = threadIdx.x >> 6;
  int v = (gid < n) ? cnt[gid] : 0;
  int x = v;
#pragma unroll
  for (int off = 1; off < 64; off <<= 1) {
    int y = __shfl_up(x, off, 64);
    if (lane >= off) x += y;
  }
  __shared__ int wt[4];
  if (lane == 63) wt[w] = x;
  __syncthreads();
  int add = 0;
  for (int i = 0; i < w; i++) add += wt[i];
  x += add;
  if (gid < n) excl[gid] = x - v;
  if (threadIdx.x == 255) bsum[blk] = x;
}

__global__ __launch_bounds__(1024) void scan_top2(int* __restrict__ bsumE, int nE,
                                                  int* __restrict__ bsumN, int nN) {
  int* bsum = blockIdx.x ? bsumN : bsumE;
  int n = blockIdx.x ? nN : nE;
  int t = threadIdx.x;
  int lane = t & 63, w = t >> 6;
  int v = (t < n) ? bsum[t] : 0;
  int x = v;
#pragma unroll
  for (int off = 1; off < 64; off <<= 1) {
    int y = __shfl_up(x, off, 64);
    if (lane >= off) x += y;
  }
  __shared__ int wt[16];
  if (lane == 63) wt[w] = x;
  __syncthreads();
  int add = 0;
  for (int i = 0; i < w; i++) add += wt[i];
  x += add;
  if (t < n) bsum[t] = x - v;
}

// ---------------- fused rowptr finalize -------------------------------------
__global__ void finalize2(const int* __restrict__ exclE, const int* __restrict__ bsumE,
                          int nE, int totE, int* __restrict__ rowE,
                          const int* __restrict__ exclN, const int* __restrict__ bsumN,
                          int nN, int totN, int* __restrict__ rowN) {
  int i = blockIdx.x * 256 + threadIdx.x;
  if (i <= nE) {
    rowE[i] = (i < nE) ? (exclE[i] + bsumE[i >> 8]) : totE;
    return;
  }
  int j = i - nE - 1;
  if (j <= nN) rowN[j] = (j < nN) ? (exclN[j] + bsumN[j >> 8]) : totN;
}

// ---------------- fused scatter (edges then nodes), permuted ids ------------
__global__ void scatter2(const int* __restrict__ ei_m, const int* __restrict__ ea_m, int Em,
                         const int* __restrict__ ei_s, const int* __restrict__ ea_s, int Es, int Nm,
                         const int* __restrict__ perm,
                         const int* __restrict__ rowptr_e, int* __restrict__ cur_e,
                         int2* __restrict__ epool,
                         const int* __restrict__ bm,
                         const int* __restrict__ bs, int Ns, int M,
                         const int* __restrict__ rowptr_n, int* __restrict__ cur_n,
                         int* __restrict__ npool) {
  int i = blockIdx.x * 256 + threadIdx.x;
  if (i < Em + Es) {
    int tgt_old, src_old, a0, a1, a2;
    if (i < Em) {
      tgt_old = ei_m[i]; src_old = ei_m[Em + i];
      a0 = ea_m[i * 3]; a1 = ea_m[i * 3 + 1]; a2 = ea_m[i * 3 + 2];
    } else {
      int j = i - Em;
      tgt_old = Nm + ei_s[j]; src_old = Nm + ei_s[Es + j];
      a0 = ea_s[j * 3]; a1 = ea_s[j * 3 + 1]; a2 = ea_s[j * 3 + 2];
    }
    int g = perm[tgt_old];
    int src = perm[src_old];
    int slot = rowptr_e[g] + atomicAdd(&cur_e[g], 1);
    epool[slot] = make_int2(src * 128, a0 | (a1 << 6) | (a2 << 12));
    return;
  }
  int k = i - (Em + Es);
  if (k >= Nm + Ns) return;
  int g = (k < Nm) ? bm[k] : (M + bs[k - Nm]);
  int node = perm[k];
  int slot = rowptr_n[g] + atomicAdd(&cur_n[g], 1);
  npool[slot] = node;
}

// ---------------- embedding over NEW ids (coalesced writes via iperm) -------
__global__ void embed2(const int* __restrict__ xm, const int* __restrict__ xs,
                       const float* __restrict__ atab, int Nm, int NTOT,
                       const int* __restrict__ iperm,
                       unsigned short* __restrict__ h) {
  int i = blockIdx.x * 256 + threadIdx.x;
  if (i >= NTOT * 32) return;
  int n = i >> 5, cq = (i & 31) * 4;
  int old = iperm[n];                 // pads -> 0 (unreferenced output)
  const int* x; const float* table; int row;
  if (old < Nm) { x = xm; table = atab + (size_t)9 * 64 * 128; row = old; }
  else { x = xs; table = atab; row = old - Nm; }
  float4 s = make_float4(0.f, 0.f, 0.f, 0.f);
#pragma unroll
  for (int f = 0; f < 9; f++) {
    int v = x[row * 9 + f];
    float4 tv = *(const float4*)(table + (size_t)(f * 64 + v) * 128 + cq);
    s.x += tv.x; s.y += tv.y; s.z += tv.z; s.w += tv.w;
  }
  us4 o;
  o.x = f2bf(s.x); o.y = f2bf(s.y); o.z = f2bf(s.z); o.w = f2bf(s.w);
  *(us4*)(h + (size_t)n * 128 + cq) = o;
}

// ---------------- fused GIN layer (unchanged from R14/R15) ------------------
__global__ __launch_bounds__(256, 4) void gin_fused3(
    const unsigned short* __restrict__ hin, unsigned short* __restrict__ hout,
    const float* __restrict__ eps_all, int l, int NmR,
    const unsigned short* __restrict__ bt16,
    const int2* __restrict__ epool, const int* __restrict__ rowptr_e,
    const unsigned short* __restrict__ w1t_a, const float* __restrict__ b1_a,
    const float* __restrict__ g1_a, const float* __restrict__ be1_a,
    const unsigned short* __restrict__ w2t_a, const float* __restrict__ b2_a,
    const float* __restrict__ g2_a, const float* __restrict__ be2_a) {
  __shared__ __align__(16) unsigned char smem[38144];
  unsigned short* z1s = (unsigned short*)smem;              // u16 idx: r*264 + c
  unsigned short* zs  = (unsigned short*)(smem + 20736);    // u16 idx: r*136 + c
  int2* recs = (int2*)smem;                                 // Phase A only (z1s dead)
  const int CAP = 2592;
  int t = threadIdx.x;
  int r0 = blockIdx.x * 64;
  int g = (r0 < NmR) ? 1 : 0;
  int gl = g * 4 + l;
  const unsigned short* bt = bt16 + (size_t)gl * 3 * 64 * 128;
  const unsigned short* w1t = w1t_a + (size_t)gl * 32768;
  const unsigned short* w2t = w2t_a + (size_t)gl * 32768;
  const float* b1 = b1_a + gl * 256;
  const float* g1 = g1_a + gl * 256;
  const float* be1 = be1_a + gl * 256;
  const float* b2 = b2_a + gl * 128;
  const float* g2 = g2_a + gl * 128;
  const float* be2 = be2_a + gl * 128;
  float eps1 = 1.0f + eps_all[gl];
  int do_relu = (l != 3);

  int e0 = rowptr_e[r0], e1 = rowptr_e[r0 + 64];
  int nE = e1 - e0;
  int nstage = (nE < CAP) ? nE : CAP;
  for (int i = t; i < nstage; i += 256) recs[i] = epool[e0 + i];
  __syncthreads();

#pragma unroll
  for (int p = 0; p < 2; p++) {
    int lr = p * 32 + (t >> 3);
    int n = r0 + lr;
    int cb = (t & 7) * 16;
    float lo[8], hi[8];
    {
      const u32* hr = (const u32*)(hin + (size_t)n * 128 + cb);
      uint4 h0v = *(const uint4*)hr;
      uint4 h1v = *(const uint4*)(hr + 4);
      u32 hd[8] = {h0v.x, h0v.y, h0v.z, h0v.w, h1v.x, h1v.y, h1v.z, h1v.w};
#pragma unroll
      for (int j = 0; j < 8; j++) {
        lo[j] = eps1 * __uint_as_float(hd[j] << 16);
        hi[j] = eps1 * __uint_as_float(hd[j] & 0xffff0000u);
      }
    }
    int le0 = rowptr_e[n] - e0, le1 = rowptr_e[n + 1] - e0;
    for (int li = le0; li < le1; li++) {
      int2 rec = (li < CAP) ? recs[li] : epool[e0 + li];
      u32 ab = (u32)rec.y;
      const u32* hs = (const u32*)(hin + rec.x + cb);
      const u32* q0 = (const u32*)(bt + (ab & 63u) * 128 + cb);
      const u32* q1 = (const u32*)(bt + (64 + ((ab >> 6) & 63u)) * 128 + cb);
      const u32* q2 = (const u32*)(bt + (128 + ((ab >> 12) & 63u)) * 128 + cb);
      uint4 A0 = *(const uint4*)hs, A1 = *(const uint4*)(hs + 4);
      uint4 B0 = *(const uint4*)q0, B1 = *(const uint4*)(q0 + 4);
      uint4 C0 = *(const uint4*)q1, C1 = *(const uint4*)(q1 + 4);
      uint4 D0 = *(const uint4*)q2, D1 = *(const uint4*)(q2 + 4);
      u32 ad[8] = {A0.x, A0.y, A0.z, A0.w, A1.x, A1.y, A1.z, A1.w};
      u32 bd[8] = {B0.x, B0.y, B0.z, B0.w, B1.x, B1.y, B1.z, B1.w};
      u32 cd[8] = {C0.x, C0.y, C0.z, C0.w, C1.x, C1.y, C1.z, C1.w};
      u32 dd[8] = {D0.x, D0.y, D0.z, D0.w, D1.x, D1.y, D1.z, D1.w};
#pragma unroll
      for (int j = 0; j < 8; j++) {
        float sl = __uint_as_float(ad[j] << 16) + __uint_as_float(bd[j] << 16)
                 + __uint_as_float(cd[j] << 16) + __uint_as_float(dd[j] << 16);
        float sh = __uint_as_float(ad[j] & 0xffff0000u) + __uint_as_float(bd[j] & 0xffff0000u)
                 + __uint_as_float(cd[j] & 0xffff0000u) + __uint_as_float(dd[j] & 0xffff0000u);
        lo[j] += fmaxf(sl, 0.f);
        hi[j] += fmaxf(sh, 0.f);
      }
    }
    u32 od[8];
#pragma unroll
    for (int j = 0; j < 8; j++)
      od[j] = (u32)f2bf(lo[j]) | (((u32)f2bf(hi[j])) << 16);
    u32* zr = (u32*)(zs + lr * 136 + cb);
    *(uint4*)zr = make_uint4(od[0], od[1], od[2], od[3]);
    *(uint4*)(zr + 4) = make_uint4(od[4], od[5], od[6], od[7]);
  }
  __syncthreads();

  int lane = t & 63, wave = t >> 6;
  int quad = lane >> 4, l16 = lane & 15;
  // Phase B
  {
    short8 bw[4][4];
    int cb = wave * 64;
#pragma unroll
    for (int nt = 0; nt < 4; nt++) {
      const unsigned short* p = w1t + (cb + nt * 16 + l16) * 128 + quad * 8;
#pragma unroll
      for (int kc = 0; kc < 4; kc++) bw[nt][kc] = *(const short8*)(p + kc * 32);
    }
    for (int mt = 0; mt < 4; mt++) {
      short8 af[4];
      const unsigned short* zrow = zs + (mt * 16 + l16) * 136 + quad * 8;
#pragma unroll
      for (int kc = 0; kc < 4; kc++)
        af[kc] = *(const short8*)(zrow + kc * 32);
#pragma unroll
      for (int nt = 0; nt < 4; nt++) {
        f32x4 acc = {0.f, 0.f, 0.f, 0.f};
#pragma unroll
        for (int kc = 0; kc < 4; kc++)
          acc = __builtin_amdgcn_mfma_f32_16x16x32_bf16(af[kc], bw[nt][kc], acc, 0, 0, 0);
        int c = cb + nt * 16 + l16;
        float sc = g1[c] * BN_RSQ, sh = be1[c], bb = b1[c];
#pragma unroll
        for (int reg = 0; reg < 4; reg++) {
          int r = mt * 16 + quad * 4 + reg;
          float y = (acc[reg] + bb) * sc + sh;
          z1s[r * 264 + c] = f2bf(fmaxf(y, 0.f));
        }
      }
      __syncthreads();
    }
  }
  // Phase C
  {
    short8 bw[2][8];
    int cb = wave * 32;
#pragma unroll
    for (int nt = 0; nt < 2; nt++) {
      const unsigned short* p = w2t + (cb + nt * 16 + l16) * 256 + quad * 8;
#pragma unroll
      for (int kc = 0; kc < 8; kc++) bw[nt][kc] = *(const short8*)(p + kc * 32);
    }
    for (int mt = 0; mt < 4; mt++) {
      short8 af[8];
      const unsigned short* zrow = z1s + (mt * 16 + l16) * 264 + quad * 8;
#pragma unroll
      for (int kc = 0; kc < 8; kc++)
        af[kc] = *(const short8*)(zrow + kc * 32);
      __syncthreads();
#pragma unroll
      for (int nt = 0; nt < 2; nt++) {
        f32x4 acc = {0.f, 0.f, 0.f, 0.f};
#pragma unroll
        for (int kc = 0; kc < 8; kc++)
          acc = __builtin_amdgcn_mfma_f32_16x16x32_bf16(af[kc], bw[nt][kc], acc, 0, 0, 0);
        int c = cb + nt * 16 + l16;
        float sc = g2[c] * BN_RSQ, sh = be2[c], bb = b2[c];
#pragma unroll
        for (int reg = 0; reg < 4; reg++) {
          int r = mt * 16 + quad * 4 + reg;
          float y = (acc[reg] + bb) * sc + sh;
          if (do_relu) y = fmaxf(y, 0.f);
          z1s[r * 264 + c] = f2bf(y);
        }
      }
    }
  }
  __syncthreads();
  for (int i = t; i < 1024; i += 256) {
    int r = i >> 4, c8 = (i & 15) * 8;
    us8 v = *(const us8*)(z1s + r * 264 + c8);
    *(us8*)(hout + (size_t)(r0 + r) * 128 + c8) = v;
  }
}

// ---------------- CSR mean pooling (256 thr, LDS npool, 2 row-groups) -------
__global__ __launch_bounds__(256) void pool_csr(const unsigned short* __restrict__ h,
                                                const int* __restrict__ npool,
                                                const int* __restrict__ rowptr_n,
                                                float* __restrict__ pooled, int nseg) {
  __shared__ int nls[512];
  __shared__ float part[128];
  int m = blockIdx.x;
  if (m >= nseg) return;
  int st = rowptr_n[m];
  int len = rowptr_n[m + 1] - st;
  int c = threadIdx.x & 127, grp = threadIdx.x >> 7;
  float s = 0.f;
  for (int base = 0; base < len; base += 512) {
    int cnt = (len - base < 512) ? (len - base) : 512;
    __syncthreads();
    for (int i = threadIdx.x; i < cnt; i += 256) nls[i] = npool[st + base + i];
    __syncthreads();
    int hh = (cnt + 1) >> 1;
    int i0 = grp * hh;
    int i1 = i0 + hh; if (i1 > cnt) i1 = cnt;
    int i = i0;
    for (; i + 3 < i1; i += 4) {
      int n0 = nls[i], n1 = nls[i + 1], n2 = nls[i + 2], n3 = nls[i + 3];
      float v0 = bf2f(h[(size_t)n0 * 128 + c]);
      float v1 = bf2f(h[(size_t)n1 * 128 + c]);
      float v2 = bf2f(h[(size_t)n2 * 128 + c]);
      float v3 = bf2f(h[(size_t)n3 * 128 + c]);
      s += (v0 + v1) + (v2 + v3);
    }
    for (; i < i1; i++) s += bf2f(h[(size_t)nls[i] * 128 + c]);
  }
  if (grp) part[c] = s;
  __syncthreads();
  if (!grp) pooled[(size_t)m * 128 + c] = (s + part[c]) / ((float)len + 1e-9f);
}

// ---------------- row GEMM (N=128): C[r,:] = A[r,:] @ W + bias --------------
__global__ __launch_bounds__(256) void gemm_tile(const float* __restrict__ A, const float* __restrict__ W,
                                                 const float* __restrict__ bias, float* __restrict__ C,
                                                 int K) {
  __shared__ float As[608];
  __shared__ float red[128];
  int r = blockIdx.x;
  int t = threadIdx.x;
  for (int i = t; i < K; i += 256) As[i] = A[(size_t)r * K + i];
  __syncthreads();
  int c = t & 127, half = t >> 7;
  int Kh = K >> 1;
  int k0 = half * Kh, k1 = k0 + Kh;
  float acc = 0.f;
#pragma unroll 8
  for (int k = k0; k < k1; k++) acc = fmaf(As[k], W[(size_t)k * 128 + c], acc);
  if (half) red[c] = acc;
  __syncthreads();
  if (!half) {
    float v = acc + red[c] + (bias ? bias[c] : 0.f);
    C[(size_t)r * 128 + c] = v;
  }
}

// ---------------- fused QKV row GEMM (K=128) --------------------------------
__global__ __launch_bounds__(256) void gemm_qkv(const float* __restrict__ A,
                                                const float* __restrict__ W0, const float* __restrict__ bi0, float* __restrict__ C0,
                                                const float* __restrict__ W1, const float* __restrict__ bi1, float* __restrict__ C1,
                                                const float* __restrict__ W2, const float* __restrict__ bi2, float* __restrict__ C2) {
  __shared__ float As[128];
  __shared__ float red[128];
  int r = blockIdx.x, which = blockIdx.y;
  const float* W = (which == 0) ? W0 : (which == 1) ? W1 : W2;
  const float* bias = (which == 0) ? bi0 : (which == 1) ? bi1 : bi2;
  float* C = (which == 0) ? C0 : (which == 1) ? C1 : C2;
  int t = threadIdx.x;
  if (t < 128) As[t] = A[(size_t)r * 128 + t];
  __syncthreads();
  int c = t & 127, half = t >> 7;
  int k0 = half * 64, k1 = k0 + 64;
  float acc = 0.f;
#pragma unroll 8
  for (int k = k0; k < k1; k++) acc = fmaf(As[k], W[(size_t)k * 128 + c], acc);
  if (half) red[c] = acc;
  __syncthreads();
  if (!half) C[(size_t)r * 128 + c] = acc + red[c] + bias[c];
}

// ---------------- fused aggQ/aggK GEMM (K=128) ------------------------------
__global__ __launch_bounds__(256) void gemm_aggqk(
    const float* __restrict__ Aq, const float* __restrict__ Wq, const float* __restrict__ bq,
    float* __restrict__ Cq, int D,
    const float* __restrict__ Ak, const float* __restrict__ Wk, const float* __restrict__ bk,
    float* __restrict__ Ck) {
  __shared__ float As[128];
  __shared__ float red[128];
  int r = blockIdx.x;
  const float* A; const float* W; const float* bias; float* C; int rr;
  if (r < D) { A = Aq; W = Wq; bias = bq; C = Cq; rr = r; }
  else { A = Ak; W = Wk; bias = bk; C = Ck; rr = r - D; }
  int t = threadIdx.x;
  if (t < 128) As[t] = A[(size_t)rr * 128 + t];
  __syncthreads();
  int c = t & 127, half = t >> 7;
  int k0 = half * 64, k1 = k0 + 64;
  float acc = 0.f;
#pragma unroll 8
  for (int k = k0; k < k1; k++) acc = fmaf(As[k], W[(size_t)k * 128 + c], acc);
  if (half) red[c] = acc;
  __syncthreads();
  if (!half) C[(size_t)rr * 128 + c] = acc + red[c] + bias[c];
}

// ---------------- fused WO GEMM + LayerNorm2 -> subf + subT (bf16 col) ------
__global__ __launch_bounds__(256) void gemm_wo_ln(const float* __restrict__ A,
                                                  const float* __restrict__ W, const float* __restrict__ bias,
                                                  const float* __restrict__ lg, const float* __restrict__ lb,
                                                  float* __restrict__ subf,
                                                  unsigned short* __restrict__ subT) {
  __shared__ float As[128];
  __shared__ float row[128];
  __shared__ float red2[4];
  int r = blockIdx.x;
  int t = threadIdx.x;
  if (t < 128) As[t] = A[(size_t)r * 128 + t];
  __syncthreads();
  int c = t & 127, half = t >> 7;
  int k0 = half * 64, k1 = k0 + 64;
  float acc = 0.f;
#pragma unroll 8
  for (int k = k0; k < k1; k++) acc = fmaf(As[k], W[(size_t)k * 128 + c], acc);
  if (half) row[c] = acc;
  __syncthreads();
  if (!half) row[c] = acc + row[c] + bias[c];
  __syncthreads();
  if (t < 128) {
    float x = row[t];
    float s = x;
    for (int off = 32; off; off >>= 1) s += __shfl_down(s, off);
    if ((t & 63) == 0) red2[t >> 6] = s;
  }
  __syncthreads();
  if (t < 128) {
    float mu = (red2[0] + red2[1]) * (1.f / 128.f);
    float dd = row[t] - mu;
    float v = dd * dd;
    for (int off = 32; off; off >>= 1) v += __shfl_down(v, off);
    if ((t & 63) == 0) red2[2 + (t >> 6)] = v;
  }
  __syncthreads();
  if (t < 128) {
    float mu = (red2[0] + red2[1]) * (1.f / 128.f);
    float var = (red2[2] + red2[3]) * (1.f / 128.f);
    float dd = row[t] - mu;
    float val = lg[t] * dd * rsqrtf(var + LN_EPS) + lb[t];
    subf[(size_t)r * 128 + t] = val;
    subT[(size_t)t * 512 + r] = f2bf(val);
  }
}

// ---------------- SAB attention: O = Qs + softmax(QsKs^T/8) Vs -------------
__global__ __launch_bounds__(256) void sab_attn(const float* __restrict__ Q, const float* __restrict__ K,
                                                const float* __restrict__ V, float* __restrict__ O, int S) {
  int q = blockIdx.x, hd = blockIdx.y;
  int t = threadIdx.x;
  __shared__ float sc[512];
  __shared__ float red[8];
  __shared__ float pacc[4][64];
  const float* qrow = Q + q * 128 + hd * 64;
  for (int k = t; k < 512; k += 256) {
    float d = -1e30f;
    if (k < S) {
      const float* krow = K + k * 128 + hd * 64;
      d = 0.f;
#pragma unroll
      for (int j = 0; j < 64; j += 4) {
        float4 a = *(const float4*)(qrow + j);
        float4 b = *(const float4*)(krow + j);
        d += a.x * b.x + a.y * b.y + a.z * b.z + a.w * b.w;
      }
      d *= 0.125f;
    }
    sc[k] = d;
  }
  __syncthreads();
  float m = fmaxf(sc[t], sc[t + 256]);
  for (int off = 32; off; off >>= 1) m = fmaxf(m, __shfl_down(m, off));
  if ((t & 63) == 0) red[t >> 6] = m;
  __syncthreads();
  m = fmaxf(fmaxf(red[0], red[1]), fmaxf(red[2], red[3]));
  float p0 = __expf(sc[t] - m), p1 = __expf(sc[t + 256] - m);
  sc[t] = p0; sc[t + 256] = p1;
  float s = p0 + p1;
  for (int off = 32; off; off >>= 1) s += __shfl_down(s, off);
  if ((t & 63) == 0) red[4 + (t >> 6)] = s;
  __syncthreads();
  float inv = 1.f / (red[4] + red[5] + red[6] + red[7]);
  int d = t & 63, part = t >> 6;
  float acc = 0.f;
  for (int k = part; k < S; k += 4) acc += sc[k] * V[k * 128 + hd * 64 + d];
  pacc[part][d] = acc;
  __syncthreads();
  if (part == 0) {
    float o = (pacc[0][d] + pacc[1][d] + pacc[2][d] + pacc[3][d]) * inv;
    O[q * 128 + hd * 64 + d] = qrow[d] + o;
  }
}

// ---------------- row LayerNorm over 128 ------------------------------------
__global__ __launch_bounds__(128) void ln_rows(const float* __restrict__ in, float* __restrict__ out,
                                               const float* __restrict__ g, const float* __restrict__ b) {
  int r = blockIdx.x, t = threadIdx.x;
  __shared__ float red[4];
  float x = in[r * 128 + t];
  float s = x;
  for (int off = 32; off; off >>= 1) s += __shfl_down(s, off);
  if ((t & 63) == 0) red[t >> 6] = s;
  __syncthreads();
  float mu = (red[0] + red[1]) * (1.f / 128.f);
  float dd = x - mu;
  float v = dd * dd;
  for (int off = 32; off; off >>= 1) v += __shfl_down(v, off);
  if ((t & 63) == 0) red[2 + (t >> 6)] = v;
  __syncthreads();
  float var = (red[2] + red[3]) * (1.f / 128.f);
  out[r * 128 + t] = g[t] * dd * rsqrtf(var + LN_EPS) + b[t];
}

// ---------------- fused masked softmax + MFMA aggregation -------------------
__global__ __launch_bounds__(256) void agg_fused(const float* __restrict__ Q, const float* __restrict__ Kt,
                                                 const void* __restrict__ mask, const int* __restrict__ flags,
                                                 const float* __restrict__ pat,
                                                 const unsigned short* __restrict__ subT,
                                                 float* __restrict__ aggT, int D, int S) {
  int d = blockIdx.x, t = threadIdx.x;
  __shared__ float sc[512];
  __shared__ float red[8];
  __shared__ unsigned short As[64][40];
  int layout = (flags[1] == 0) ? 0 : (flags[0] ? 1 : 2);
  const float* qrow = Q + d * 128;
  for (int s = t; s < 512; s += 256) {
    float v = NEGBIG;
    if (s < S) {
      int mi = d * S + s;
      bool msk;
      if (layout == 0)      msk = ((const int*)mask)[mi] != 0;
      else if (layout == 1) msk = ((const unsigned char*)mask)[mi] != 0;
      else                  msk = ((const float*)mask)[mi] != 0.f;
      if (!msk) {
        float dd = 0.f;
        const float* krow = Kt + s * 128;
#pragma unroll
        for (int j = 0; j < 128; j += 4) {
          float4 a = *(const float4*)(qrow + j);
          float4 b = *(const float4*)(krow + j);
          dd += a.x * b.x + a.y * b.y + a.z * b.z + a.w * b.w;
        }
        v = dd * 0.08838834764831845f;
      }
    }
    sc[s] = v;
  }
  __syncthreads();
  float m = fmaxf(sc[t], sc[t + 256]);
  for (int off = 32; off; off >>= 1) m = fmaxf(m, __shfl_down(m, off));
  if ((t & 63) == 0) red[t >> 6] = m;
  __syncthreads();
  m = fmaxf(fmaxf(red[0], red[1]), fmaxf(red[2], red[3]));
  float p0 = __expf(sc[t] - m), p1 = __expf(sc[t + 256] - m);
  float s2 = p0 + p1;
  for (int off = 32; off; off >>= 1) s2 += __shfl_down(s2, off);
  if ((t & 63) == 0) red[4 + (t >> 6)] = s2;
  __syncthreads();
  float inv = 1.f / (red[4] + red[5] + red[6] + red[7]);
  sc[t] = p0 * inv;
  sc[t + 256] = p1 * inv;
  __syncthreads();

  int lane = t & 63, wave = t >> 6;
  int quad = lane >> 4, l16 = lane & 15;
  f32x4 acc[8];
#pragma unroll
  for (int nt = 0; nt < 8; nt++) acc[nt] = (f32x4){0.f, 0.f, 0.f, 0.f};
  int srow = t >> 2, skb = (t & 3) * 8;
  for (int c = 0; c < 16; c++) {
    int s0 = c * 32;
    __syncthreads();
    unsigned short v[8];
#pragma unroll
    for (int j = 0; j < 8; j++) {
      int s = s0 + skb + j;
      float x = (s < S) ? sc[s] * pat[srow * S + s] : 0.f;
      v[j] = f2bf(x);
    }
    *(us4*)&As[srow][skb]     = *(us4*)&v[0];
    *(us4*)&As[srow][skb + 4] = *(us4*)&v[4];
    __syncthreads();
    short8 af = *(const short8*)&As[16 * wave + l16][quad * 8];
#pragma unroll
    for (int nt = 0; nt < 8; nt++) {
      short8 bf = *(const short8*)(subT + (nt * 16 + l16) * 512 + s0 + quad * 8);
      acc[nt] = __builtin_amdgcn_mfma_f32_16x16x32_bf16(af, bf, acc[nt], 0, 0, 0);
    }
  }
#pragma unroll
  for (int nt = 0; nt < 8; nt++) {
    int hh = nt * 16 + l16;
#pragma unroll
    for (int reg = 0; reg < 4; reg++) {
      int b = 16 * wave + quad * 4 + reg;
      aggT[((size_t)(b * D + d)) * 128 + hh] = acc[nt][reg];
    }
  }
}

// ---------------- score head ------------------------------------------------
__global__ __launch_bounds__(256) void score_head(const float* __restrict__ aggT,
                                                  const float* __restrict__ w1, const float* __restrict__ b1,
                                                  const float* __restrict__ w2, const float* __restrict__ b2,
                                                  float* __restrict__ out, int total) {
  int i = blockIdx.x * 4 + (threadIdx.x >> 6);
  int j = threadIdx.x & 63;
  if (i >= total) return;
  const float* av = aggT + (size_t)i * 128;
  float acc = b1[j];
#pragma unroll 8
  for (int k = 0; k < 128; k++) acc = fmaf(av[k], w1[k * 64 + j], acc);
  acc = fmaxf(acc, 0.f) * w2[j];
  for (int off = 32; off; off >>= 1) acc += __shfl_down(acc, off);
  if (j == 0) {
    float x = acc + b2[0];
    out[i] = 1.f / (1.f + __expf(-x));
  }
}

// ---------------------------------------------------------------------------
extern "C" void kernel_launch(void* const* d_in, const int* in_sizes, int n_in,
                              void* d_out, int out_size, void* d_ws, size_t ws_size,
                              hipStream_t stream) {
  const float* atom_emb = (const float*)d_in[0];
  const float* bond_emb = (const float*)d_in[1];
  const float* gin_eps  = (const float*)d_in[2];
  const float* gin_w1   = (const float*)d_in[3];
  const float* gin_b1   = (const float*)d_in[4];
  const float* bn1g     = (const float*)d_in[5];
  const float* bn1b     = (const float*)d_in[6];
  const float* gin_w2   = (const float*)d_in[7];
  const float* gin_b2   = (const float*)d_in[8];
  const float* bn2g     = (const float*)d_in[9];
  const float* bn2b     = (const float*)d_in[10];
  const float* sab_wq = (const float*)d_in[11];
  const float* sab_wk = (const float*)d_in[12];
  const float* sab_wv = (const float*)d_in[13];
  const float* sab_wo = (const float*)d_in[14];
  const float* sab_bq = (const float*)d_in[15];
  const float* sab_bk = (const float*)d_in[16];
  const float* sab_bv = (const float*)d_in[17];
  const float* sab_bo = (const float*)d_in[18];
  const float* ln1b = (const float*)d_in[19];
  const float* ln2b = (const float*)d_in[20];
  const float* ln1g = (const float*)d_in[21];
  const float* ln2g = (const float*)d_in[22];
  const float* agg_wq = (const float*)d_in[23];
  const float* agg_bq = (const float*)d_in[24];
  const float* agg_wk = (const float*)d_in[25];
  const float* agg_bk = (const float*)d_in[26];
  const float* score_w1 = (const float*)d_in[27];
  const float* score_b1 = (const float*)d_in[28];
  const float* score_w2 = (const float*)d_in[29];
  const float* score_b2 = (const float*)d_in[30];
  const float* patient  = (const float*)d_in[31];
  const float* avgproj  = (const float*)d_in[32];
  const int* sub_x     = (const int*)d_in[33];
  const int* sub_ea    = (const int*)d_in[34];
  const int* sub_ei    = (const int*)d_in[35];
  const int* sub_batch = (const int*)d_in[36];
  const int* mol_x     = (const int*)d_in[37];
  const int* mol_ea    = (const int*)d_in[38];
  const int* mol_ei    = (const int*)d_in[39];
  const int* mol_batch = (const int*)d_in[40];
  const void* mask     = d_in[41];

  const int Ns = in_sizes[33] / 9, Es = in_sizes[34] / 3;
  const int Nm = in_sizes[37] / 9, Em = in_sizes[38] / 3;
  const int S = 492, M = 600, D = 200, B = 64;
  const int NmR = (Nm + 63) & ~63;
  const int NsR = (Ns + 63) & ~63;
  const int NTOT = NmR + NsR;
  const int NSEG = M + S;
  const int ETOT = Em + Es;
  const int NOLD = Nm + Ns;
  const int BONDE = 2 * 4 * 3 * 64 * 128;

  // ---- workspace carve-up ----
  char* Wp = (char*)d_ws;
  size_t off = 0;
  auto alloc = [&](size_t bytes) -> void* {
    void* p = Wp + off;
    off = (off + bytes + 255) & ~(size_t)255;
    return p;
  };
  unsigned short* h0 = (unsigned short*)alloc((size_t)NTOT * 128 * 2);
  unsigned short* h1 = (unsigned short*)alloc((size_t)NTOT * 128 * 2);
  unsigned short* w1t = (unsigned short*)alloc(262144 * 2);
  unsigned short* w2t = (unsigned short*)alloc(262144 * 2);
  unsigned short* bt16 = (unsigned short*)alloc((size_t)BONDE * 2);
  int2* epool  = (int2*)alloc((size_t)ETOT * 8);
  int*  npool  = (int*)alloc((size_t)NOLD * 4);
  int*  perm   = (int*)alloc((size_t)NOLD * 4);
  int*  excl_e = (int*)alloc((size_t)NTOT * 4);
  int*  bsum_e = (int*)alloc(1024 * 4);
  int*  excl_n = (int*)alloc((size_t)NSEG * 4);
  int*  bsum_n = (int*)alloc(1024 * 4);
  int*  rowptr_e = (int*)alloc((size_t)(NTOT + 1) * 4);
  int*  rowptr_n = (int*)alloc((size_t)(NSEG + 1) * 4);
  int*  binbase = (int*)alloc(128 * 4);
  char* zstart = Wp + off;                       // region zeroed below
  int*  deg_old = (int*)alloc((size_t)NOLD * 4);
  int*  deg_e  = (int*)alloc((size_t)NTOT * 4);  // permuted degrees
  int*  deg_n  = (int*)alloc((size_t)NSEG * 4);
  int*  cur_e  = (int*)alloc((size_t)NTOT * 4);
  int*  cur_n  = (int*)alloc((size_t)NSEG * 4);
  int*  hist   = (int*)alloc(128 * 4);
  int*  bincur = (int*)alloc(128 * 4);
  int*  iperm  = (int*)alloc((size_t)NTOT * 4);  // pads -> 0
  int*  flags  = (int*)alloc(8);
  unsigned short* subT = (unsigned short*)alloc((size_t)128 * 512 * 2);   // zeroed pads
  size_t zsize = (size_t)((Wp + off) - zstart);
  float* pooled_all = (float*)alloc((size_t)NSEG * 128 * 4);
  float* pooled_mol = pooled_all;
  float* pooled_sub = pooled_all + (size_t)M * 128;
  float* Qb   = (float*)alloc((size_t)S * 128 * 4);
  float* Kb   = (float*)alloc((size_t)S * 128 * 4);
  float* Vb   = (float*)alloc((size_t)S * 128 * 4);
  float* Ob   = (float*)alloc((size_t)S * 128 * 4);
  float* subf = (float*)alloc((size_t)S * 128 * 4);
  float* mol_embb = (float*)alloc((size_t)D * 128 * 4);
  float* aggQb = (float*)alloc((size_t)D * 128 * 4);
  float* aggKb = (float*)alloc((size_t)S * 128 * 4);
  float* aggTb = (float*)alloc((size_t)B * D * 128 * 4);
  (void)ws_size; (void)n_in; (void)out_size;

  hipMemsetAsync(zstart, 0, zsize, stream);
  prep_all<<<1856, 256, 0, stream>>>(gin_w1, gin_w2, w1t, w2t,
                                     bond_emb, bt16, BONDE,
                                     (const unsigned char*)mask, flags, D * S);

  // ---- degree-sorted CSR build ----
  int total_cnt = Em + Es + Nm + Ns;
  build_count_old<<<(total_cnt + 255) / 256, 256, 0, stream>>>(
      mol_ei, Em, sub_ei, Es, mol_batch, Nm, sub_batch, Ns, deg_old, deg_n, M);
  deg_hist<<<(NOLD + 255) / 256, 256, 0, stream>>>(deg_old, Nm, NOLD, hist);
  hist_scan<<<1, 128, 0, stream>>>(hist, binbase);
  perm_assign<<<(NOLD + 255) / 256, 256, 0, stream>>>(
      deg_old, Nm, NOLD, NmR, binbase, bincur, perm, iperm, deg_e);
  int nb_e = (NTOT + 255) / 256;
  int nb_n = (NSEG + 255) / 256;
  scan_block2<<<nb_e + nb_n, 256, 0, stream>>>(deg_e, NTOT, excl_e, bsum_e, nb_e,
                                               deg_n, NSEG, excl_n, bsum_n);
  scan_top2<<<2, 1024, 0, stream>>>(bsum_e, nb_e, bsum_n, nb_n);
  finalize2<<<((NTOT + 1) + (NSEG + 1) + 1 + 255) / 256, 256, 0, stream>>>(
      excl_e, bsum_e, NTOT, ETOT, rowptr_e,
      excl_n, bsum_n, NSEG, NOLD, rowptr_n);
  scatter2<<<(ETOT + NOLD + 255) / 256, 256, 0, stream>>>(
      mol_ei, mol_ea, Em, sub_ei, sub_ea, Es, Nm, perm, rowptr_e, cur_e, epool,
      mol_batch, sub_batch, Ns, M, rowptr_n, cur_n, npool);

  // ---- merged GIN over permuted ids ----
  embed2<<<(NTOT * 32 + 255) / 256, 256, 0, stream>>>(
      mol_x, sub_x, atom_emb, Nm, NTOT, iperm, h0);
  unsigned short* hin = h0; unsigned short* hout = h1;
  for (int l = 0; l < 4; l++) {
    gin_fused3<<<NTOT / 64, 256, 0, stream>>>(
        hin, hout, gin_eps, l, NmR, bt16, epool, rowptr_e,
        w1t, gin_b1, bn1g, bn1b, w2t, gin_b2, bn2g, bn2b);
    unsigned short* tmp = hin; hin = hout; hout = tmp;
  }
  pool_csr<<<NSEG, 256, 0, stream>>>(hin, npool, rowptr_n, pooled_all, NSEG);

  // --- SAB on sub pooled ---
  gemm_qkv<<<dim3(S, 3), 256, 0, stream>>>(pooled_sub,
                                           sab_wq, sab_bq, Qb,
                                           sab_wk, sab_bk, Kb,
                                           sab_wv, sab_bv, Vb);
  sab_attn<<<dim3(S, 2), 256, 0, stream>>>(Qb, Kb, Vb, Ob, S);
  ln_rows<<<S, 128, 0, stream>>>(Ob, Ob, ln1g, ln1b);
  gemm_wo_ln<<<S, 256, 0, stream>>>(Ob, sab_wo, sab_bo, ln2g, ln2b, subf, subT);

  // --- molecule projection ---
  gemm_tile<<<D, 256, 0, stream>>>(avgproj, pooled_mol, (const float*)nullptr, mol_embb, 600);

  // --- attention aggregation + score ---
  gemm_aggqk<<<D + S, 256, 0, stream>>>(mol_embb, agg_wq, agg_bq, aggQb, D,
                                        subf, agg_wk, agg_bk, aggKb);
  agg_fused<<<D, 256, 0, stream>>>(aggQb, aggKb, mask, flags, patient, subT, aggTb, D, S);
  score_head<<<(B * D + 3) / 4, 256, 0, stream>>>(aggTb, score_w1, score_b1, score_w2, score_b2,
                                                  (float*)d_out, B * D);
}

// Round 18
// 917.233 us; speedup vs baseline: 2.6322x; 2.6322x over previous
//
#include <hip/hip_runtime.h>

// ---------------------------------------------------------------------------
// MoleRec pipeline on gfx950.
// R17: R16's degree-sort build kernels re-committed the R8 same-address
//      atomic sin (210K atomicAdds on 128 counters -> perm_assign 755us,
//      deg_hist similar). Replaced by two-level counting sort: per-block LDS
//      histograms; <=128 global atomics per block; intra-block rank from LDS
//      atomicAdd return value. Sort semantics unchanged (any within-bin
//      order is a valid bijection). GIN/tail unchanged from R16.
// ---------------------------------------------------------------------------

typedef short short8 __attribute__((ext_vector_type(8)));
typedef unsigned short us8 __attribute__((ext_vector_type(8)));
typedef float f32x4 __attribute__((ext_vector_type(4)));
typedef unsigned short us4 __attribute__((ext_vector_type(4)));
typedef unsigned int u32;

#define BN_RSQ 0.9999950000374997f   // 1/sqrt(1+1e-5)  (BatchNorm eval, var=1)
#define LN_EPS 1e-5f
#define NEGBIG -4294967296.0f        // -(1<<32), matches reference mask fill

__device__ __forceinline__ unsigned short f2bf(float x) {
  union { float f; unsigned int u; } v; v.f = x;
  unsigned int r = v.u + 0x7fffu + ((v.u >> 16) & 1u);   // RNE
  return (unsigned short)(r >> 16);
}
__device__ __forceinline__ float bf2f(unsigned short x) {
  union { unsigned int u; float f; } v; v.u = ((unsigned int)x) << 16;
  return v.f;
}

// ---------------- fused prep: weights + bond tables + mask detect -----------
__global__ __launch_bounds__(256) void prep_all(
    const float* __restrict__ w1, const float* __restrict__ w2,
    unsigned short* __restrict__ w1t, unsigned short* __restrict__ w2t,
    const float* __restrict__ bond, unsigned short* __restrict__ bt16, int bonde,
    const unsigned char* __restrict__ m, int* __restrict__ flags, int maskn) {
  __shared__ int lf[2];
  int b = blockIdx.x;
  if (b < 1024) {
    int i = b * 256 + threadIdx.x;
    int gl = i >> 15;
    int k1 = (i >> 8) & 127, c1 = i & 255;
    w1t[(gl << 15) + c1 * 128 + k1] = f2bf(w1[i]);
    int k2 = (i >> 7) & 255, c2 = i & 127;
    w2t[(gl << 15) + c2 * 256 + k2] = f2bf(w2[i]);
    return;
  }
  if (b < 1792) {
    int i = (b - 1024) * 256 + threadIdx.x;
    if (i < bonde) bt16[i] = f2bf(bond[i]);
    return;
  }
  if (threadIdx.x == 0) { lf[0] = 0; lf[1] = 0; }
  __syncthreads();
  int f0 = 0, f1 = 0;
  for (int i = (b - 1792) * 256 + threadIdx.x; i < maskn; i += 64 * 256) {
    if (m[i]) { if ((i & 3) == 0) f0 = 1; else f1 = 1; }
  }
  if (f0) atomicOr(&lf[0], 1);
  if (f1) atomicOr(&lf[1], 1);
  __syncthreads();
  if (threadIdx.x == 0) {
    if (lf[0]) atomicOr(flags, 1);
    if (lf[1]) atomicOr(flags + 1, 1);
  }
}

// ---------------- degree count over compact old ids + batch counts ----------
__global__ void build_count_old(const int* __restrict__ ei_m, int Em,
                                const int* __restrict__ ei_s, int Es,
                                const int* __restrict__ bm, int Nm,
                                const int* __restrict__ bs, int Ns,
                                int* __restrict__ deg_old, int* __restrict__ deg_n, int M) {
  int i = blockIdx.x * 256 + threadIdx.x;
  if (i < Em) { atomicAdd(&deg_old[ei_m[i]], 1); return; }
  i -= Em;
  if (i < Es) { atomicAdd(&deg_old[Nm + ei_s[i]], 1); return; }
  i -= Es;
  if (i < Nm) { atomicAdd(&deg_n[bm[i]], 1); return; }
  i -= Nm;
  if (i < Ns) { atomicAdd(&deg_n[M + bs[i]], 1); }
}

// ---------------- degree histogram, block-aggregated (R17) ------------------
__global__ __launch_bounds__(256) void deg_hist2(const int* __restrict__ deg_old, int Nm, int Ntot,
                                                 int* __restrict__ hist) {
  __shared__ int lh[128];
  if (threadIdx.x < 128) lh[threadIdx.x] = 0;
  __syncthreads();
  int i = blockIdx.x * 256 + threadIdx.x;
  if (i < Ntot) {
    int d = deg_old[i]; if (d > 63) d = 63;
    int r = (i < Nm) ? 0 : 1;
    atomicAdd(&lh[r * 64 + d], 1);
  }
  __syncthreads();
  if (threadIdx.x < 128 && lh[threadIdx.x]) atomicAdd(&hist[threadIdx.x], lh[threadIdx.x]);
}

// ---------------- per-region exclusive scan of 64 bins ----------------------
__global__ __launch_bounds__(128) void hist_scan(const int* __restrict__ hist,
                                                 int* __restrict__ binbase) {
  int t = threadIdx.x;
  int lane = t & 63;
  int v = hist[t];
  int x = v;
#pragma unroll
  for (int off = 1; off < 64; off <<= 1) {
    int y = __shfl_up(x, off, 64);
    if (lane >= off) x += y;
  }
  binbase[t] = x - v;
}

// ---------------- perm assign, block-aggregated (R17) -----------------------
__global__ __launch_bounds__(256) void perm_assign2(const int* __restrict__ deg_old,
                                                    int Nm, int Ntot, int NmR,
                                                    const int* __restrict__ binbase,
                                                    int* __restrict__ bincur,
                                                    int* __restrict__ perm, int* __restrict__ iperm,
                                                    int* __restrict__ deg_new) {
  __shared__ int lh[128];
  __shared__ int gbase[128];
  if (threadIdx.x < 128) lh[threadIdx.x] = 0;
  __syncthreads();
  int i = blockIdx.x * 256 + threadIdx.x;
  int bin = 0, lrank = 0, dg = 0;
  bool valid = (i < Ntot);
  if (valid) {
    dg = deg_old[i];
    int d = (dg > 63) ? 63 : dg;
    int r = (i < Nm) ? 0 : 1;
    bin = r * 64 + d;
    lrank = atomicAdd(&lh[bin], 1);     // LDS atomic return = intra-block rank
  }
  __syncthreads();
  if (threadIdx.x < 128 && lh[threadIdx.x])
    gbase[threadIdx.x] = atomicAdd(&bincur[threadIdx.x], lh[threadIdx.x]);
  __syncthreads();
  if (valid) {
    int slot = binbase[bin] + gbase[bin] + lrank;
    int nid = ((bin >= 64) ? NmR : 0) + slot;
    perm[i] = nid;
    iperm[nid] = i;
    deg_new[nid] = dg;
  }
}

// ---------------- fused block scans (edges then nodes) ----------------------
__global__ __launch_bounds__(256) void scan_block2(
    const int* __restrict__ cntE, int nE, int* __restrict__ exclE, int* __restrict__ bsumE, int nbE,
    const int* __restrict__ cntN, int nN, int* __restrict__ exclN, int* __restrict__ bsumN) {
  const int* cnt; int n; int* excl; int* bsum; int blk;
  if (blockIdx.x < (unsigned)nbE) { cnt = cntE; n = nE; excl = exclE; bsum = bsumE; blk = blockIdx.x; }
  else { cnt = cntN; n = nN; excl = exclN; bsum = bsumN; blk = blockIdx.x - nbE; }
  int gid = blk * 256 + threadIdx.x;
  int lane = threadIdx.x & 63, w = threadIdx.x >> 6;
  int v = (gid < n) ? cnt[gid] : 0;
  int x = v;
#pragma unroll
  for (int off = 1; off < 64; off <<= 1) {
    int y = __shfl_up(x, off, 64);
    if (lane >= off) x += y;
  }
  __shared__ int wt[4];
  if (lane == 63) wt[w] = x;
  __syncthreads();
  int add = 0;
  for (int i = 0; i < w; i++) add += wt[i];
  x += add;
  if (gid < n) excl[gid] = x - v;
  if (threadIdx.x == 255) bsum[blk] = x;
}

__global__ __launch_bounds__(1024) void scan_top2(int* __restrict__ bsumE, int nE,
                                                  int* __restrict__ bsumN, int nN) {
  int* bsum = blockIdx.x ? bsumN : bsumE;
  int n = blockIdx.x ? nN : nE;
  int t = threadIdx.x;
  int lane = t & 63, w = t >> 6;
  int v = (t < n) ? bsum[t] : 0;
  int x = v;
#pragma unroll
  for (int off = 1; off < 64; off <<= 1) {
    int y = __shfl_up(x, off, 64);
    if (lane >= off) x += y;
  }
  __shared__ int wt[16];
  if (lane == 63) wt[w] = x;
  __syncthreads();
  int add = 0;
  for (int i = 0; i < w; i++) add += wt[i];
  x += add;
  if (t < n) bsum[t] = x - v;
}

// ---------------- fused rowptr finalize -------------------------------------
__global__ void finalize2(const int* __restrict__ exclE, const int* __restrict__ bsumE,
                          int nE, int totE, int* __restrict__ rowE,
                          const int* __restrict__ exclN, const int* __restrict__ bsumN,
                          int nN, int totN, int* __restrict__ rowN) {
  int i = blockIdx.x * 256 + threadIdx.x;
  if (i <= nE) {
    rowE[i] = (i < nE) ? (exclE[i] + bsumE[i >> 8]) : totE;
    return;
  }
  int j = i - nE - 1;
  if (j <= nN) rowN[j] = (j < nN) ? (exclN[j] + bsumN[j >> 8]) : totN;
}

// ---------------- fused scatter (edges then nodes), permuted ids ------------
__global__ void scatter2(const int* __restrict__ ei_m, const int* __restrict__ ea_m, int Em,
                         const int* __restrict__ ei_s, const int* __restrict__ ea_s, int Es, int Nm,
                         const int* __restrict__ perm,
                         const int* __restrict__ rowptr_e, int* __restrict__ cur_e,
                         int2* __restrict__ epool,
                         const int* __restrict__ bm,
                         const int* __restrict__ bs, int Ns, int M,
                         const int* __restrict__ rowptr_n, int* __restrict__ cur_n,
                         int* __restrict__ npool) {
  int i = blockIdx.x * 256 + threadIdx.x;
  if (i < Em + Es) {
    int tgt_old, src_old, a0, a1, a2;
    if (i < Em) {
      tgt_old = ei_m[i]; src_old = ei_m[Em + i];
      a0 = ea_m[i * 3]; a1 = ea_m[i * 3 + 1]; a2 = ea_m[i * 3 + 2];
    } else {
      int j = i - Em;
      tgt_old = Nm + ei_s[j]; src_old = Nm + ei_s[Es + j];
      a0 = ea_s[j * 3]; a1 = ea_s[j * 3 + 1]; a2 = ea_s[j * 3 + 2];
    }
    int g = perm[tgt_old];
    int src = perm[src_old];
    int slot = rowptr_e[g] + atomicAdd(&cur_e[g], 1);
    epool[slot] = make_int2(src * 128, a0 | (a1 << 6) | (a2 << 12));
    return;
  }
  int k = i - (Em + Es);
  if (k >= Nm + Ns) return;
  int g = (k < Nm) ? bm[k] : (M + bs[k - Nm]);
  int node = perm[k];
  int slot = rowptr_n[g] + atomicAdd(&cur_n[g], 1);
  npool[slot] = node;
}

// ---------------- embedding over NEW ids ------------------------------------
__global__ void embed2(const int* __restrict__ xm, const int* __restrict__ xs,
                       const float* __restrict__ atab, int Nm, int NTOT,
                       const int* __restrict__ iperm,
                       unsigned short* __restrict__ h) {
  int i = blockIdx.x * 256 + threadIdx.x;
  if (i >= NTOT * 32) return;
  int n = i >> 5, cq = (i & 31) * 4;
  int old = iperm[n];
  const int* x; const float* table; int row;
  if (old < Nm) { x = xm; table = atab + (size_t)9 * 64 * 128; row = old; }
  else { x = xs; table = atab; row = old - Nm; }
  float4 s = make_float4(0.f, 0.f, 0.f, 0.f);
#pragma unroll
  for (int f = 0; f < 9; f++) {
    int v = x[row * 9 + f];
    float4 tv = *(const float4*)(table + (size_t)(f * 64 + v) * 128 + cq);
    s.x += tv.x; s.y += tv.y; s.z += tv.z; s.w += tv.w;
  }
  us4 o;
  o.x = f2bf(s.x); o.y = f2bf(s.y); o.z = f2bf(s.z); o.w = f2bf(s.w);
  *(us4*)(h + (size_t)n * 128 + cq) = o;
}

// ---------------- fused GIN layer (unchanged) -------------------------------
__global__ __launch_bounds__(256, 4) void gin_fused3(
    const unsigned short* __restrict__ hin, unsigned short* __restrict__ hout,
    const float* __restrict__ eps_all, int l, int NmR,
    const unsigned short* __restrict__ bt16,
    const int2* __restrict__ epool, const int* __restrict__ rowptr_e,
    const unsigned short* __restrict__ w1t_a, const float* __restrict__ b1_a,
    const float* __restrict__ g1_a, const float* __restrict__ be1_a,
    const unsigned short* __restrict__ w2t_a, const float* __restrict__ b2_a,
    const float* __restrict__ g2_a, const float* __restrict__ be2_a) {
  __shared__ __align__(16) unsigned char smem[38144];
  unsigned short* z1s = (unsigned short*)smem;              // u16 idx: r*264 + c
  unsigned short* zs  = (unsigned short*)(smem + 20736);    // u16 idx: r*136 + c
  int2* recs = (int2*)smem;
  const int CAP = 2592;
  int t = threadIdx.x;
  int r0 = blockIdx.x * 64;
  int g = (r0 < NmR) ? 1 : 0;
  int gl = g * 4 + l;
  const unsigned short* bt = bt16 + (size_t)gl * 3 * 64 * 128;
  const unsigned short* w1t = w1t_a + (size_t)gl * 32768;
  const unsigned short* w2t = w2t_a + (size_t)gl * 32768;
  const float* b1 = b1_a + gl * 256;
  const float* g1 = g1_a + gl * 256;
  const float* be1 = be1_a + gl * 256;
  const float* b2 = b2_a + gl * 128;
  const float* g2 = g2_a + gl * 128;
  const float* be2 = be2_a + gl * 128;
  float eps1 = 1.0f + eps_all[gl];
  int do_relu = (l != 3);

  int e0 = rowptr_e[r0], e1 = rowptr_e[r0 + 64];
  int nE = e1 - e0;
  int nstage = (nE < CAP) ? nE : CAP;
  for (int i = t; i < nstage; i += 256) recs[i] = epool[e0 + i];
  __syncthreads();

#pragma unroll
  for (int p = 0; p < 2; p++) {
    int lr = p * 32 + (t >> 3);
    int n = r0 + lr;
    int cb = (t & 7) * 16;
    float lo[8], hi[8];
    {
      const u32* hr = (const u32*)(hin + (size_t)n * 128 + cb);
      uint4 h0v = *(const uint4*)hr;
      uint4 h1v = *(const uint4*)(hr + 4);
      u32 hd[8] = {h0v.x, h0v.y, h0v.z, h0v.w, h1v.x, h1v.y, h1v.z, h1v.w};
#pragma unroll
      for (int j = 0; j < 8; j++) {
        lo[j] = eps1 * __uint_as_float(hd[j] << 16);
        hi[j] = eps1 * __uint_as_float(hd[j] & 0xffff0000u);
      }
    }
    int le0 = rowptr_e[n] - e0, le1 = rowptr_e[n + 1] - e0;
    for (int li = le0; li < le1; li++) {
      int2 rec = (li < CAP) ? recs[li] : epool[e0 + li];
      u32 ab = (u32)rec.y;
      const u32* hs = (const u32*)(hin + rec.x + cb);
      const u32* q0 = (const u32*)(bt + (ab & 63u) * 128 + cb);
      const u32* q1 = (const u32*)(bt + (64 + ((ab >> 6) & 63u)) * 128 + cb);
      const u32* q2 = (const u32*)(bt + (128 + ((ab >> 12) & 63u)) * 128 + cb);
      uint4 A0 = *(const uint4*)hs, A1 = *(const uint4*)(hs + 4);
      uint4 B0 = *(const uint4*)q0, B1 = *(const uint4*)(q0 + 4);
      uint4 C0 = *(const uint4*)q1, C1 = *(const uint4*)(q1 + 4);
      uint4 D0 = *(const uint4*)q2, D1 = *(const uint4*)(q2 + 4);
      u32 ad[8] = {A0.x, A0.y, A0.z, A0.w, A1.x, A1.y, A1.z, A1.w};
      u32 bd[8] = {B0.x, B0.y, B0.z, B0.w, B1.x, B1.y, B1.z, B1.w};
      u32 cd[8] = {C0.x, C0.y, C0.z, C0.w, C1.x, C1.y, C1.z, C1.w};
      u32 dd[8] = {D0.x, D0.y, D0.z, D0.w, D1.x, D1.y, D1.z, D1.w};
#pragma unroll
      for (int j = 0; j < 8; j++) {
        float sl = __uint_as_float(ad[j] << 16) + __uint_as_float(bd[j] << 16)
                 + __uint_as_float(cd[j] << 16) + __uint_as_float(dd[j] << 16);
        float sh = __uint_as_float(ad[j] & 0xffff0000u) + __uint_as_float(bd[j] & 0xffff0000u)
                 + __uint_as_float(cd[j] & 0xffff0000u) + __uint_as_float(dd[j] & 0xffff0000u);
        lo[j] += fmaxf(sl, 0.f);
        hi[j] += fmaxf(sh, 0.f);
      }
    }
    u32 od[8];
#pragma unroll
    for (int j = 0; j < 8; j++)
      od[j] = (u32)f2bf(lo[j]) | (((u32)f2bf(hi[j])) << 16);
    u32* zr = (u32*)(zs + lr * 136 + cb);
    *(uint4*)zr = make_uint4(od[0], od[1], od[2], od[3]);
    *(uint4*)(zr + 4) = make_uint4(od[4], od[5], od[6], od[7]);
  }
  __syncthreads();

  int lane = t & 63, wave = t >> 6;
  int quad = lane >> 4, l16 = lane & 15;
  // Phase B
  {
    short8 bw[4][4];
    int cb = wave * 64;
#pragma unroll
    for (int nt = 0; nt < 4; nt++) {
      const unsigned short* p = w1t + (cb + nt * 16 + l16) * 128 + quad * 8;
#pragma unroll
      for (int kc = 0; kc < 4; kc++) bw[nt][kc] = *(const short8*)(p + kc * 32);
    }
    for (int mt = 0; mt < 4; mt++) {
      short8 af[4];
      const unsigned short* zrow = zs + (mt * 16 + l16) * 136 + quad * 8;
#pragma unroll
      for (int kc = 0; kc < 4; kc++)
        af[kc] = *(const short8*)(zrow + kc * 32);
#pragma unroll
      for (int nt = 0; nt < 4; nt++) {
        f32x4 acc = {0.f, 0.f, 0.f, 0.f};
#pragma unroll
        for (int kc = 0; kc < 4; kc++)
          acc = __builtin_amdgcn_mfma_f32_16x16x32_bf16(af[kc], bw[nt][kc], acc, 0, 0, 0);
        int c = cb + nt * 16 + l16;
        float sc = g1[c] * BN_RSQ, sh = be1[c], bb = b1[c];
#pragma unroll
        for (int reg = 0; reg < 4; reg++) {
          int r = mt * 16 + quad * 4 + reg;
          float y = (acc[reg] + bb) * sc + sh;
          z1s[r * 264 + c] = f2bf(fmaxf(y, 0.f));
        }
      }
      __syncthreads();
    }
  }
  // Phase C
  {
    short8 bw[2][8];
    int cb = wave * 32;
#pragma unroll
    for (int nt = 0; nt < 2; nt++) {
      const unsigned short* p = w2t + (cb + nt * 16 + l16) * 256 + quad * 8;
#pragma unroll
      for (int kc = 0; kc < 8; kc++) bw[nt][kc] = *(const short8*)(p + kc * 32);
    }
    for (int mt = 0; mt < 4; mt++) {
      short8 af[8];
      const unsigned short* zrow = z1s + (mt * 16 + l16) * 264 + quad * 8;
#pragma unroll
      for (int kc = 0; kc < 8; kc++)
        af[kc] = *(const short8*)(zrow + kc * 32);
      __syncthreads();
#pragma unroll
      for (int nt = 0; nt < 2; nt++) {
        f32x4 acc = {0.f, 0.f, 0.f, 0.f};
#pragma unroll
        for (int kc = 0; kc < 8; kc++)
          acc = __builtin_amdgcn_mfma_f32_16x16x32_bf16(af[kc], bw[nt][kc], acc, 0, 0, 0);
        int c = cb + nt * 16 + l16;
        float sc = g2[c] * BN_RSQ, sh = be2[c], bb = b2[c];
#pragma unroll
        for (int reg = 0; reg < 4; reg++) {
          int r = mt * 16 + quad * 4 + reg;
          float y = (acc[reg] + bb) * sc + sh;
          if (do_relu) y = fmaxf(y, 0.f);
          z1s[r * 264 + c] = f2bf(y);
        }
      }
    }
  }
  __syncthreads();
  for (int i = t; i < 1024; i += 256) {
    int r = i >> 4, c8 = (i & 15) * 8;
    us8 v = *(const us8*)(z1s + r * 264 + c8);
    *(us8*)(hout + (size_t)(r0 + r) * 128 + c8) = v;
  }
}

// ---------------- CSR mean pooling ------------------------------------------
__global__ __launch_bounds__(256) void pool_csr(const unsigned short* __restrict__ h,
                                                const int* __restrict__ npool,
                                                const int* __restrict__ rowptr_n,
                                                float* __restrict__ pooled, int nseg) {
  __shared__ int nls[512];
  __shared__ float part[128];
  int m = blockIdx.x;
  if (m >= nseg) return;
  int st = rowptr_n[m];
  int len = rowptr_n[m + 1] - st;
  int c = threadIdx.x & 127, grp = threadIdx.x >> 7;
  float s = 0.f;
  for (int base = 0; base < len; base += 512) {
    int cnt = (len - base < 512) ? (len - base) : 512;
    __syncthreads();
    for (int i = threadIdx.x; i < cnt; i += 256) nls[i] = npool[st + base + i];
    __syncthreads();
    int hh = (cnt + 1) >> 1;
    int i0 = grp * hh;
    int i1 = i0 + hh; if (i1 > cnt) i1 = cnt;
    int i = i0;
    for (; i + 3 < i1; i += 4) {
      int n0 = nls[i], n1 = nls[i + 1], n2 = nls[i + 2], n3 = nls[i + 3];
      float v0 = bf2f(h[(size_t)n0 * 128 + c]);
      float v1 = bf2f(h[(size_t)n1 * 128 + c]);
      float v2 = bf2f(h[(size_t)n2 * 128 + c]);
      float v3 = bf2f(h[(size_t)n3 * 128 + c]);
      s += (v0 + v1) + (v2 + v3);
    }
    for (; i < i1; i++) s += bf2f(h[(size_t)nls[i] * 128 + c]);
  }
  if (grp) part[c] = s;
  __syncthreads();
  if (!grp) pooled[(size_t)m * 128 + c] = (s + part[c]) / ((float)len + 1e-9f);
}

// ---------------- row GEMM (N=128) ------------------------------------------
__global__ __launch_bounds__(256) void gemm_tile(const float* __restrict__ A, const float* __restrict__ W,
                                                 const float* __restrict__ bias, float* __restrict__ C,
                                                 int K) {
  __shared__ float As[608];
  __shared__ float red[128];
  int r = blockIdx.x;
  int t = threadIdx.x;
  for (int i = t; i < K; i += 256) As[i] = A[(size_t)r * K + i];
  __syncthreads();
  int c = t & 127, half = t >> 7;
  int Kh = K >> 1;
  int k0 = half * Kh, k1 = k0 + Kh;
  float acc = 0.f;
#pragma unroll 8
  for (int k = k0; k < k1; k++) acc = fmaf(As[k], W[(size_t)k * 128 + c], acc);
  if (half) red[c] = acc;
  __syncthreads();
  if (!half) {
    float v = acc + red[c] + (bias ? bias[c] : 0.f);
    C[(size_t)r * 128 + c] = v;
  }
}

// ---------------- fused QKV row GEMM (K=128) --------------------------------
__global__ __launch_bounds__(256) void gemm_qkv(const float* __restrict__ A,
                                                const float* __restrict__ W0, const float* __restrict__ bi0, float* __restrict__ C0,
                                                const float* __restrict__ W1, const float* __restrict__ bi1, float* __restrict__ C1,
                                                const float* __restrict__ W2, const float* __restrict__ bi2, float* __restrict__ C2) {
  __shared__ float As[128];
  __shared__ float red[128];
  int r = blockIdx.x, which = blockIdx.y;
  const float* W = (which == 0) ? W0 : (which == 1) ? W1 : W2;
  const float* bias = (which == 0) ? bi0 : (which == 1) ? bi1 : bi2;
  float* C = (which == 0) ? C0 : (which == 1) ? C1 : C2;
  int t = threadIdx.x;
  if (t < 128) As[t] = A[(size_t)r * 128 + t];
  __syncthreads();
  int c = t & 127, half = t >> 7;
  int k0 = half * 64, k1 = k0 + 64;
  float acc = 0.f;
#pragma unroll 8
  for (int k = k0; k < k1; k++) acc = fmaf(As[k], W[(size_t)k * 128 + c], acc);
  if (half) red[c] = acc;
  __syncthreads();
  if (!half) C[(size_t)r * 128 + c] = acc + red[c] + bias[c];
}

// ---------------- fused aggQ/aggK GEMM (K=128) ------------------------------
__global__ __launch_bounds__(256) void gemm_aggqk(
    const float* __restrict__ Aq, const float* __restrict__ Wq, const float* __restrict__ bq,
    float* __restrict__ Cq, int D,
    const float* __restrict__ Ak, const float* __restrict__ Wk, const float* __restrict__ bk,
    float* __restrict__ Ck) {
  __shared__ float As[128];
  __shared__ float red[128];
  int r = blockIdx.x;
  const float* A; const float* W; const float* bias; float* C; int rr;
  if (r < D) { A = Aq; W = Wq; bias = bq; C = Cq; rr = r; }
  else { A = Ak; W = Wk; bias = bk; C = Ck; rr = r - D; }
  int t = threadIdx.x;
  if (t < 128) As[t] = A[(size_t)rr * 128 + t];
  __syncthreads();
  int c = t & 127, half = t >> 7;
  int k0 = half * 64, k1 = k0 + 64;
  float acc = 0.f;
#pragma unroll 8
  for (int k = k0; k < k1; k++) acc = fmaf(As[k], W[(size_t)k * 128 + c], acc);
  if (half) red[c] = acc;
  __syncthreads();
  if (!half) C[(size_t)rr * 128 + c] = acc + red[c] + bias[c];
}

// ---------------- fused WO GEMM + LayerNorm2 -> subf + subT -----------------
__global__ __launch_bounds__(256) void gemm_wo_ln(const float* __restrict__ A,
                                                  const float* __restrict__ W, const float* __restrict__ bias,
                                                  const float* __restrict__ lg, const float* __restrict__ lb,
                                                  float* __restrict__ subf,
                                                  unsigned short* __restrict__ subT) {
  __shared__ float As[128];
  __shared__ float row[128];
  __shared__ float red2[4];
  int r = blockIdx.x;
  int t = threadIdx.x;
  if (t < 128) As[t] = A[(size_t)r * 128 + t];
  __syncthreads();
  int c = t & 127, half = t >> 7;
  int k0 = half * 64, k1 = k0 + 64;
  float acc = 0.f;
#pragma unroll 8
  for (int k = k0; k < k1; k++) acc = fmaf(As[k], W[(size_t)k * 128 + c], acc);
  if (half) row[c] = acc;
  __syncthreads();
  if (!half) row[c] = acc + row[c] + bias[c];
  __syncthreads();
  if (t < 128) {
    float x = row[t];
    float s = x;
    for (int off = 32; off; off >>= 1) s += __shfl_down(s, off);
    if ((t & 63) == 0) red2[t >> 6] = s;
  }
  __syncthreads();
  if (t < 128) {
    float mu = (red2[0] + red2[1]) * (1.f / 128.f);
    float dd = row[t] - mu;
    float v = dd * dd;
    for (int off = 32; off; off >>= 1) v += __shfl_down(v, off);
    if ((t & 63) == 0) red2[2 + (t >> 6)] = v;
  }
  __syncthreads();
  if (t < 128) {
    float mu = (red2[0] + red2[1]) * (1.f / 128.f);
    float var = (red2[2] + red2[3]) * (1.f / 128.f);
    float dd = row[t] - mu;
    float val = lg[t] * dd * rsqrtf(var + LN_EPS) + lb[t];
    subf[(size_t)r * 128 + t] = val;
    subT[(size_t)t * 512 + r] = f2bf(val);
  }
}

// ---------------- SAB attention ---------------------------------------------
__global__ __launch_bounds__(256) void sab_attn(const float* __restrict__ Q, const float* __restrict__ K,
                                                const float* __restrict__ V, float* __restrict__ O, int S) {
  int q = blockIdx.x, hd = blockIdx.y;
  int t = threadIdx.x;
  __shared__ float sc[512];
  __shared__ float red[8];
  __shared__ float pacc[4][64];
  const float* qrow = Q + q * 128 + hd * 64;
  for (int k = t; k < 512; k += 256) {
    float d = -1e30f;
    if (k < S) {
      const float* krow = K + k * 128 + hd * 64;
      d = 0.f;
#pragma unroll
      for (int j = 0; j < 64; j += 4) {
        float4 a = *(const float4*)(qrow + j);
        float4 b = *(const float4*)(krow + j);
        d += a.x * b.x + a.y * b.y + a.z * b.z + a.w * b.w;
      }
      d *= 0.125f;
    }
    sc[k] = d;
  }
  __syncthreads();
  float m = fmaxf(sc[t], sc[t + 256]);
  for (int off = 32; off; off >>= 1) m = fmaxf(m, __shfl_down(m, off));
  if ((t & 63) == 0) red[t >> 6] = m;
  __syncthreads();
  m = fmaxf(fmaxf(red[0], red[1]), fmaxf(red[2], red[3]));
  float p0 = __expf(sc[t] - m), p1 = __expf(sc[t + 256] - m);
  sc[t] = p0; sc[t + 256] = p1;
  float s = p0 + p1;
  for (int off = 32; off; off >>= 1) s += __shfl_down(s, off);
  if ((t & 63) == 0) red[4 + (t >> 6)] = s;
  __syncthreads();
  float inv = 1.f / (red[4] + red[5] + red[6] + red[7]);
  int d = t & 63, part = t >> 6;
  float acc = 0.f;
  for (int k = part; k < S; k += 4) acc += sc[k] * V[k * 128 + hd * 64 + d];
  pacc[part][d] = acc;
  __syncthreads();
  if (part == 0) {
    float o = (pacc[0][d] + pacc[1][d] + pacc[2][d] + pacc[3][d]) * inv;
    O[q * 128 + hd * 64 + d] = qrow[d] + o;
  }
}

// ---------------- row LayerNorm over 128 ------------------------------------
__global__ __launch_bounds__(128) void ln_rows(const float* __restrict__ in, float* __restrict__ out,
                                               const float* __restrict__ g, const float* __restrict__ b) {
  int r = blockIdx.x, t = threadIdx.x;
  __shared__ float red[4];
  float x = in[r * 128 + t];
  float s = x;
  for (int off = 32; off; off >>= 1) s += __shfl_down(s, off);
  if ((t & 63) == 0) red[t >> 6] = s;
  __syncthreads();
  float mu = (red[0] + red[1]) * (1.f / 128.f);
  float dd = x - mu;
  float v = dd * dd;
  for (int off = 32; off; off >>= 1) v += __shfl_down(v, off);
  if ((t & 63) == 0) red[2 + (t >> 6)] = v;
  __syncthreads();
  float var = (red[2] + red[3]) * (1.f / 128.f);
  out[r * 128 + t] = g[t] * dd * rsqrtf(var + LN_EPS) + b[t];
}

// ---------------- fused masked softmax + MFMA aggregation -------------------
__global__ __launch_bounds__(256) void agg_fused(const float* __restrict__ Q, const float* __restrict__ Kt,
                                                 const void* __restrict__ mask, const int* __restrict__ flags,
                                                 const float* __restrict__ pat,
                                                 const unsigned short* __restrict__ subT,
                                                 float* __restrict__ aggT, int D, int S) {
  int d = blockIdx.x, t = threadIdx.x;
  __shared__ float sc[512];
  __shared__ float red[8];
  __shared__ unsigned short As[64][40];
  int layout = (flags[1] == 0) ? 0 : (flags[0] ? 1 : 2);
  const float* qrow = Q + d * 128;
  for (int s = t; s < 512; s += 256) {
    float v = NEGBIG;
    if (s < S) {
      int mi = d * S + s;
      bool msk;
      if (layout == 0)      msk = ((const int*)mask)[mi] != 0;
      else if (layout == 1) msk = ((const unsigned char*)mask)[mi] != 0;
      else                  msk = ((const float*)mask)[mi] != 0.f;
      if (!msk) {
        float dd = 0.f;
        const float* krow = Kt + s * 128;
#pragma unroll
        for (int j = 0; j < 128; j += 4) {
          float4 a = *(const float4*)(qrow + j);
          float4 b = *(const float4*)(krow + j);
          dd += a.x * b.x + a.y * b.y + a.z * b.z + a.w * b.w;
        }
        v = dd * 0.08838834764831845f;
      }
    }
    sc[s] = v;
  }
  __syncthreads();
  float m = fmaxf(sc[t], sc[t + 256]);
  for (int off = 32; off; off >>= 1) m = fmaxf(m, __shfl_down(m, off));
  if ((t & 63) == 0) red[t >> 6] = m;
  __syncthreads();
  m = fmaxf(fmaxf(red[0], red[1]), fmaxf(red[2], red[3]));
  float p0 = __expf(sc[t] - m), p1 = __expf(sc[t + 256] - m);
  float s2 = p0 + p1;
  for (int off = 32; off; off >>= 1) s2 += __shfl_down(s2, off);
  if ((t & 63) == 0) red[4 + (t >> 6)] = s2;
  __syncthreads();
  float inv = 1.f / (red[4] + red[5] + red[6] + red[7]);
  sc[t] = p0 * inv;
  sc[t + 256] = p1 * inv;
  __syncthreads();

  int lane = t & 63, wave = t >> 6;
  int quad = lane >> 4, l16 = lane & 15;
  f32x4 acc[8];
#pragma unroll
  for (int nt = 0; nt < 8; nt++) acc[nt] = (f32x4){0.f, 0.f, 0.f, 0.f};
  int srow = t >> 2, skb = (t & 3) * 8;
  for (int c = 0; c < 16; c++) {
    int s0 = c * 32;
    __syncthreads();
    unsigned short v[8];
#pragma unroll
    for (int j = 0; j < 8; j++) {
      int s = s0 + skb + j;
      float x = (s < S) ? sc[s] * pat[srow * S + s] : 0.f;
      v[j] = f2bf(x);
    }
    *(us4*)&As[srow][skb]     = *(us4*)&v[0];
    *(us4*)&As[srow][skb + 4] = *(us4*)&v[4];
    __syncthreads();
    short8 af = *(const short8*)&As[16 * wave + l16][quad * 8];
#pragma unroll
    for (int nt = 0; nt < 8; nt++) {
      short8 bf = *(const short8*)(subT + (nt * 16 + l16) * 512 + s0 + quad * 8);
      acc[nt] = __builtin_amdgcn_mfma_f32_16x16x32_bf16(af, bf, acc[nt], 0, 0, 0);
    }
  }
#pragma unroll
  for (int nt = 0; nt < 8; nt++) {
    int hh = nt * 16 + l16;
#pragma unroll
    for (int reg = 0; reg < 4; reg++) {
      int b = 16 * wave + quad * 4 + reg;
      aggT[((size_t)(b * D + d)) * 128 + hh] = acc[nt][reg];
    }
  }
}

// ---------------- score head ------------------------------------------------
__global__ __launch_bounds__(256) void score_head(const float* __restrict__ aggT,
                                                  const float* __restrict__ w1, const float* __restrict__ b1,
                                                  const float* __restrict__ w2, const float* __restrict__ b2,
                                                  float* __restrict__ out, int total) {
  int i = blockIdx.x * 4 + (threadIdx.x >> 6);
  int j = threadIdx.x & 63;
  if (i >= total) return;
  const float* av = aggT + (size_t)i * 128;
  float acc = b1[j];
#pragma unroll 8
  for (int k = 0; k < 128; k++) acc = fmaf(av[k], w1[k * 64 + j], acc);
  acc = fmaxf(acc, 0.f) * w2[j];
  for (int off = 32; off; off >>= 1) acc += __shfl_down(acc, off);
  if (j == 0) {
    float x = acc + b2[0];
    out[i] = 1.f / (1.f + __expf(-x));
  }
}

// ---------------------------------------------------------------------------
extern "C" void kernel_launch(void* const* d_in, const int* in_sizes, int n_in,
                              void* d_out, int out_size, void* d_ws, size_t ws_size,
                              hipStream_t stream) {
  const float* atom_emb = (const float*)d_in[0];
  const float* bond_emb = (const float*)d_in[1];
  const float* gin_eps  = (const float*)d_in[2];
  const float* gin_w1   = (const float*)d_in[3];
  const float* gin_b1   = (const float*)d_in[4];
  const float* bn1g     = (const float*)d_in[5];
  const float* bn1b     = (const float*)d_in[6];
  const float* gin_w2   = (const float*)d_in[7];
  const float* gin_b2   = (const float*)d_in[8];
  const float* bn2g     = (const float*)d_in[9];
  const float* bn2b     = (const float*)d_in[10];
  const float* sab_wq = (const float*)d_in[11];
  const float* sab_wk = (const float*)d_in[12];
  const float* sab_wv = (const float*)d_in[13];
  const float* sab_wo = (const float*)d_in[14];
  const float* sab_bq = (const float*)d_in[15];
  const float* sab_bk = (const float*)d_in[16];
  const float* sab_bv = (const float*)d_in[17];
  const float* sab_bo = (const float*)d_in[18];
  const float* ln1b = (const float*)d_in[19];
  const float* ln2b = (const float*)d_in[20];
  const float* ln1g = (const float*)d_in[21];
  const float* ln2g = (const float*)d_in[22];
  const float* agg_wq = (const float*)d_in[23];
  const float* agg_bq = (const float*)d_in[24];
  const float* agg_wk = (const float*)d_in[25];
  const float* agg_bk = (const float*)d_in[26];
  const float* score_w1 = (const float*)d_in[27];
  const float* score_b1 = (const float*)d_in[28];
  const float* score_w2 = (const float*)d_in[29];
  const float* score_b2 = (const float*)d_in[30];
  const float* patient  = (const float*)d_in[31];
  const float* avgproj  = (const float*)d_in[32];
  const int* sub_x     = (const int*)d_in[33];
  const int* sub_ea    = (const int*)d_in[34];
  const int* sub_ei    = (const int*)d_in[35];
  const int* sub_batch = (const int*)d_in[36];
  const int* mol_x     = (const int*)d_in[37];
  const int* mol_ea    = (const int*)d_in[38];
  const int* mol_ei    = (const int*)d_in[39];
  const int* mol_batch = (const int*)d_in[40];
  const void* mask     = d_in[41];

  const int Ns = in_sizes[33] / 9, Es = in_sizes[34] / 3;
  const int Nm = in_sizes[37] / 9, Em = in_sizes[38] / 3;
  const int S = 492, M = 600, D = 200, B = 64;
  const int NmR = (Nm + 63) & ~63;
  const int NsR = (Ns + 63) & ~63;
  const int NTOT = NmR + NsR;
  const int NSEG = M + S;
  const int ETOT = Em + Es;
  const int NOLD = Nm + Ns;
  const int BONDE = 2 * 4 * 3 * 64 * 128;

  // ---- workspace carve-up ----
  char* Wp = (char*)d_ws;
  size_t off = 0;
  auto alloc = [&](size_t bytes) -> void* {
    void* p = Wp + off;
    off = (off + bytes + 255) & ~(size_t)255;
    return p;
  };
  unsigned short* h0 = (unsigned short*)alloc((size_t)NTOT * 128 * 2);
  unsigned short* h1 = (unsigned short*)alloc((size_t)NTOT * 128 * 2);
  unsigned short* w1t = (unsigned short*)alloc(262144 * 2);
  unsigned short* w2t = (unsigned short*)alloc(262144 * 2);
  unsigned short* bt16 = (unsigned short*)alloc((size_t)BONDE * 2);
  int2* epool  = (int2*)alloc((size_t)ETOT * 8);
  int*  npool  = (int*)alloc((size_t)NOLD * 4);
  int*  perm   = (int*)alloc((size_t)NOLD * 4);
  int*  excl_e = (int*)alloc((size_t)NTOT * 4);
  int*  bsum_e = (int*)alloc(1024 * 4);
  int*  excl_n = (int*)alloc((size_t)NSEG * 4);
  int*  bsum_n = (int*)alloc(1024 * 4);
  int*  rowptr_e = (int*)alloc((size_t)(NTOT + 1) * 4);
  int*  rowptr_n = (int*)alloc((size_t)(NSEG + 1) * 4);
  int*  binbase = (int*)alloc(128 * 4);
  char* zstart = Wp + off;                       // region zeroed below
  int*  deg_old = (int*)alloc((size_t)NOLD * 4);
  int*  deg_e  = (int*)alloc((size_t)NTOT * 4);
  int*  deg_n  = (int*)alloc((size_t)NSEG * 4);
  int*  cur_e  = (int*)alloc((size_t)NTOT * 4);
  int*  cur_n  = (int*)alloc((size_t)NSEG * 4);
  int*  hist   = (int*)alloc(128 * 4);
  int*  bincur = (int*)alloc(128 * 4);
  int*  iperm  = (int*)alloc((size_t)NTOT * 4);
  int*  flags  = (int*)alloc(8);
  unsigned short* subT = (unsigned short*)alloc((size_t)128 * 512 * 2);
  size_t zsize = (size_t)((Wp + off) - zstart);
  float* pooled_all = (float*)alloc((size_t)NSEG * 128 * 4);
  float* pooled_mol = pooled_all;
  float* pooled_sub = pooled_all + (size_t)M * 128;
  float* Qb   = (float*)alloc((size_t)S * 128 * 4);
  float* Kb   = (float*)alloc((size_t)S * 128 * 4);
  float* Vb   = (float*)alloc((size_t)S * 128 * 4);
  float* Ob   = (float*)alloc((size_t)S * 128 * 4);
  float* subf = (float*)alloc((size_t)S * 128 * 4);
  float* mol_embb = (float*)alloc((size_t)D * 128 * 4);
  float* aggQb = (float*)alloc((size_t)D * 128 * 4);
  float* aggKb = (float*)alloc((size_t)S * 128 * 4);
  float* aggTb = (float*)alloc((size_t)B * D * 128 * 4);
  (void)ws_size; (void)n_in; (void)out_size;

  hipMemsetAsync(zstart, 0, zsize, stream);
  prep_all<<<1856, 256, 0, stream>>>(gin_w1, gin_w2, w1t, w2t,
                                     bond_emb, bt16, BONDE,
                                     (const unsigned char*)mask, flags, D * S);

  // ---- degree-sorted CSR build (contention-free) ----
  int total_cnt = Em + Es + Nm + Ns;
  build_count_old<<<(total_cnt + 255) / 256, 256, 0, stream>>>(
      mol_ei, Em, sub_ei, Es, mol_batch, Nm, sub_batch, Ns, deg_old, deg_n, M);
  deg_hist2<<<(NOLD + 255) / 256, 256, 0, stream>>>(deg_old, Nm, NOLD, hist);
  hist_scan<<<1, 128, 0, stream>>>(hist, binbase);
  perm_assign2<<<(NOLD + 255) / 256, 256, 0, stream>>>(
      deg_old, Nm, NOLD, NmR, binbase, bincur, perm, iperm, deg_e);
  int nb_e = (NTOT + 255) / 256;
  int nb_n = (NSEG + 255) / 256;
  scan_block2<<<nb_e + nb_n, 256, 0, stream>>>(deg_e, NTOT, excl_e, bsum_e, nb_e,
                                               deg_n, NSEG, excl_n, bsum_n);
  scan_top2<<<2, 1024, 0, stream>>>(bsum_e, nb_e, bsum_n, nb_n);
  finalize2<<<((NTOT + 1) + (NSEG + 1) + 1 + 255) / 256, 256, 0, stream>>>(
      excl_e, bsum_e, NTOT, ETOT, rowptr_e,
      excl_n, bsum_n, NSEG, NOLD, rowptr_n);
  scatter2<<<(ETOT + NOLD + 255) / 256, 256, 0, stream>>>(
      mol_ei, mol_ea, Em, sub_ei, sub_ea, Es, Nm, perm, rowptr_e, cur_e, epool,
      mol_batch, sub_batch, Ns, M, rowptr_n, cur_n, npool);

  // ---- merged GIN over permuted ids ----
  embed2<<<(NTOT * 32 + 255) / 256, 256, 0, stream>>>(
      mol_x, sub_x, atom_emb, Nm, NTOT, iperm, h0);
  unsigned short* hin = h0; unsigned short* hout = h1;
  for (int l = 0; l < 4; l++) {
    gin_fused3<<<NTOT / 64, 256, 0, stream>>>(
        hin, hout, gin_eps, l, NmR, bt16, epool, rowptr_e,
        w1t, gin_b1, bn1g, bn1b, w2t, gin_b2, bn2g, bn2b);
    unsigned short* tmp = hin; hin = hout; hout = tmp;
  }
  pool_csr<<<NSEG, 256, 0, stream>>>(hin, npool, rowptr_n, pooled_all, NSEG);

  // --- SAB on sub pooled ---
  gemm_qkv<<<dim3(S, 3), 256, 0, stream>>>(pooled_sub,
                                           sab_wq, sab_bq, Qb,
                                           sab_wk, sab_bk, Kb,
                                           sab_wv, sab_bv, Vb);
  sab_attn<<<dim3(S, 2), 256, 0, stream>>>(Qb, Kb, Vb, Ob, S);
  ln_rows<<<S, 128, 0, stream>>>(Ob, Ob, ln1g, ln1b);
  gemm_wo_ln<<<S, 256, 0, stream>>>(Ob, sab_wo, sab_bo, ln2g, ln2b, subf, subT);

  // --- molecule projection ---
  gemm_tile<<<D, 256, 0, stream>>>(avgproj, pooled_mol, (const float*)nullptr, mol_embb, 600);

  // --- attention aggregation + score ---
  gemm_aggqk<<<D + S, 256, 0, stream>>>(mol_embb, agg_wq, agg_bq, aggQb, D,
                                        subf, agg_wk, agg_bk, aggKb);
  agg_fused<<<D, 256, 0, stream>>>(aggQb, aggKb, mask, flags, patient, subT, aggTb, D, S);
  score_head<<<(B * D + 3) / 4, 256, 0, stream>>>(aggTb, score_w1, score_b1, score_w2, score_b2,
                                                  (float*)d_out, B * D);
}